// Round 10
// baseline (3989.792 us; speedup 1.0000x reference)
//
#include <hip/hip_runtime.h>
#include <hip/hip_bf16.h>

// GRU restructured (v10): barrier-free epoch-tagged exchange.
//   Exchange values travel as atomic u32 = bf16 | (epoch<<16): data and
//   readiness fused in one store -> consumers validate epochs embedded in the
//   coop load itself. No flags, no vmcnt-drain-before-flag, no poll RTT.
//   Parity double-buffer + dependency-chain skew bound make reuse race-free.
//   Everything else = v9: pinned weights (asm "+v"), LDS staging for MFMA
//   A-frags, all-wave redundant h finalize via RED, P(t+1) prefetch.

#define EMB 512
#define HID 1024
#define BATCHN 64
#define TLEN 512
#define CAT 1536
#define GROUPS 4
#define GB 16
#define WPG 32            // WGs per group (each owns 32 cols)
#define HX_LD 1032        // hx leading dim: uniform-bank b128 reads
#define ZL_LD 34
#define GPAD 8

typedef __attribute__((ext_vector_type(8))) short bf16x8;
typedef __attribute__((ext_vector_type(4))) short s16x4;
typedef __attribute__((ext_vector_type(4))) float f32x4;
typedef unsigned int u32;
typedef unsigned long long u64;
typedef unsigned short u16;

__device__ __forceinline__ float bf2f(u16 u) {
  union { float f; u32 i; } v; v.i = ((u32)u) << 16; return v.f;
}
__device__ __forceinline__ u16 f2bf(float f) {
  union { float f; u32 i; } v; v.f = f;
  u32 r = v.i + 0x7fffu + ((v.i >> 16) & 1u);
  return (u16)(r >> 16);
}

// Agent-scope relaxed atomics (verified primitives, v4-v9).
__device__ __forceinline__ u64 ld_dc64(const u32* p) {
  return __hip_atomic_load((const u64*)p, __ATOMIC_RELAXED, __HIP_MEMORY_SCOPE_AGENT);
}
__device__ __forceinline__ void st_dc32(u32* p, u32 v) {
  __hip_atomic_store(p, v, __ATOMIC_RELAXED, __HIP_MEMORY_SCOPE_AGENT);
}

// ---------------- phase 0: weight conversion ----------------
__global__ __launch_bounds__(256) void convert_gate_w(const float* __restrict__ W,
                                                      u16* __restrict__ Wh_,
                                                      u16* __restrict__ Wx_) {
  int i = blockIdx.x * 256 + threadIdx.x;
  if (i >= HID * CAT) return;
  int row = i / CAT, col = i - row * CAT;
  u16 v = f2bf(W[i]);
  if (col < HID) Wh_[row * HID + col] = v;
  else           Wx_[row * EMB + (col - HID)] = v;
}

__global__ __launch_bounds__(256) void convert_wy(const float* __restrict__ W, u16* __restrict__ Wy_) {
  int i = blockIdx.x * 256 + threadIdx.x;
  if (i < EMB * HID) Wy_[i] = f2bf(W[i]);
}

// ---------------- phase 1: P = shift(word) @ Wx.T + bias ----------------
__global__ __launch_bounds__(256) void proj_kernel(const float* __restrict__ word,
                                                   const u16* __restrict__ Wx,
                                                   const float* __restrict__ bias,
                                                   u16* __restrict__ P) {
  __shared__ __align__(16) u16 As[64][64 + GPAD];
  __shared__ __align__(16) u16 Bs[64][64 + GPAD];
  const int tid = threadIdx.x;
  const int wid = tid >> 6, lane = tid & 63;
  const int m0 = blockIdx.x * 64, n0 = blockIdx.y * 64;
  const int mw = (wid >> 1) * 32, nw = (wid & 1) * 32;
  f32x4 acc[2][2] = {};
  for (int k0 = 0; k0 < EMB; k0 += 64) {
#pragma unroll
    for (int it = 0; it < 4; ++it) {
      int e = (it * 256 + tid) * 4;
      int row = e >> 6, col = e & 63;
      int R = m0 + row;
      float4 a = make_float4(0.f, 0.f, 0.f, 0.f);
      if ((R & (TLEN - 1)) != 0)
        a = *reinterpret_cast<const float4*>(&word[(u64)(R - 1) * EMB + k0 + col]);
      s16x4 vv;
      vv[0] = (short)f2bf(a.x); vv[1] = (short)f2bf(a.y);
      vv[2] = (short)f2bf(a.z); vv[3] = (short)f2bf(a.w);
      *reinterpret_cast<s16x4*>(&As[row][col]) = vv;
    }
#pragma unroll
    for (int it = 0; it < 2; ++it) {
      int e = (it * 256 + tid) * 8;
      int row = e >> 6, col = e & 63;
      *reinterpret_cast<bf16x8*>(&Bs[row][col]) =
          *reinterpret_cast<const bf16x8*>(&Wx[(u64)(n0 + row) * EMB + k0 + col]);
    }
    __syncthreads();
#pragma unroll
    for (int kk = 0; kk < 2; ++kk) {
      const int kb = kk * 32 + 8 * (lane >> 4);
#pragma unroll
      for (int i = 0; i < 2; ++i) {
        bf16x8 a = *reinterpret_cast<const bf16x8*>(&As[mw + i * 16 + (lane & 15)][kb]);
#pragma unroll
        for (int j = 0; j < 2; ++j) {
          bf16x8 b = *reinterpret_cast<const bf16x8*>(&Bs[nw + j * 16 + (lane & 15)][kb]);
          acc[i][j] = __builtin_amdgcn_mfma_f32_16x16x32_bf16(a, b, acc[i][j], 0, 0, 0);
        }
      }
    }
    __syncthreads();
  }
#pragma unroll
  for (int i = 0; i < 2; ++i)
#pragma unroll
    for (int j = 0; j < 2; ++j) {
      int col = n0 + nw + j * 16 + (lane & 15);
      float bv = bias[col];
#pragma unroll
      for (int q = 0; q < 4; ++q) {
        int row = m0 + mw + i * 16 + 4 * (lane >> 4) + q;
        P[(u64)row * HID + col] = f2bf(acc[i][j][q] + bv);
      }
    }
}

// ---------------- phase 3: out = H @ Wy.T + by (fp32 out) ----------------
__global__ __launch_bounds__(256) void out_gemm(const u16* __restrict__ H,
                                                const u16* __restrict__ Wy,
                                                const float* __restrict__ by,
                                                float* __restrict__ out) {
  __shared__ __align__(16) u16 As[64][64 + GPAD];
  __shared__ __align__(16) u16 Bs[64][64 + GPAD];
  const int tid = threadIdx.x;
  const int wid = tid >> 6, lane = tid & 63;
  const int m0 = blockIdx.x * 64, n0 = blockIdx.y * 64;
  const int mw = (wid >> 1) * 32, nw = (wid & 1) * 32;
  f32x4 acc[2][2] = {};
  for (int k0 = 0; k0 < HID; k0 += 64) {
#pragma unroll
    for (int it = 0; it < 2; ++it) {
      int e = (it * 256 + tid) * 8;
      int row = e >> 6, col = e & 63;
      *reinterpret_cast<bf16x8*>(&As[row][col]) =
          *reinterpret_cast<const bf16x8*>(&H[(u64)(m0 + row) * HID + k0 + col]);
      *reinterpret_cast<bf16x8*>(&Bs[row][col]) =
          *reinterpret_cast<const bf16x8*>(&Wy[(u64)(n0 + row) * HID + k0 + col]);
    }
    __syncthreads();
#pragma unroll
    for (int kk = 0; kk < 2; ++kk) {
      const int kb = kk * 32 + 8 * (lane >> 4);
#pragma unroll
      for (int i = 0; i < 2; ++i) {
        bf16x8 a = *reinterpret_cast<const bf16x8*>(&As[mw + i * 16 + (lane & 15)][kb]);
#pragma unroll
        for (int j = 0; j < 2; ++j) {
          bf16x8 b = *reinterpret_cast<const bf16x8*>(&Bs[nw + j * 16 + (lane & 15)][kb]);
          acc[i][j] = __builtin_amdgcn_mfma_f32_16x16x32_bf16(a, b, acc[i][j], 0, 0, 0);
        }
      }
    }
    __syncthreads();
  }
#pragma unroll
  for (int i = 0; i < 2; ++i)
#pragma unroll
    for (int j = 0; j < 2; ++j) {
      int col = n0 + nw + j * 16 + (lane & 15);
      float bv = by[col];
#pragma unroll
      for (int q = 0; q < 4; ++q) {
        int row = m0 + mw + i * 16 + 4 * (lane >> 4) + q;
        out[(u64)row * EMB + col] = acc[i][j][q] + bv;
      }
    }
}

// ---------------- phase 2: persistent recurrent kernel ----------------
__global__ __launch_bounds__(256, 1) void gru_persistent(
    const u16* __restrict__ Wzh, const u16* __restrict__ Wrh, const u16* __restrict__ Whh,
    const u16* __restrict__ Pz, const u16* __restrict__ Pr, u16* __restrict__ PhH,
    u32* __restrict__ rhbuf32, u32* __restrict__ hxbuf32) {
  // LDS ~38.2 KB: hx (staging) + zL + RED.
  __shared__ __align__(16) u16 hx[16 * HX_LD];
  __shared__ __align__(16) u16 zL[16 * ZL_LD];
  __shared__ __align__(16) float RED[4 * 64 * 4];

  const int tid = threadIdx.x;
  const int wid = tid >> 6;
  const int lane = tid & 63;
  const int l15 = lane & 15;
  const int k4 = lane >> 4;  // 0..3
  const int g = blockIdx.x & (GROUPS - 1);
  const int w = blockIdx.x >> 2;  // 0..31, owns cols [32w, 32w+32)
  const int b0 = g * GB;
  const int j = wid & 1;        // 16-col tile within the 32
  const int gate = wid >> 1;    // stage A: 0 = z, 1 = r
  const int kh = wid >> 1;      // stage B: K-half
  const int colA = 32 * w + 16 * j + l15;
  const u16* __restrict__ PA = gate ? Pr : Pz;

  // coop poll-load decomposition: thread = (row srow, 32 u64 chunks at
  // u32-offset (tid&15)*2 + 32*i) -> 128B-coalesced slabs.
  const int srow = tid >> 4;
  const int soff = (tid & 15) * 2;

  // ---- weights -> registers, PINNED (asm "+v" blocks rematerialization) ----
  bf16x8 wfA[32];
#pragma unroll
  for (int s = 0; s < 32; ++s)
    wfA[s] = *reinterpret_cast<const bf16x8*>(
        (gate ? Wrh : Wzh) + (u64)colA * HID + 32 * s + k4 * 8);
  bf16x8 wfB[16];
#pragma unroll
  for (int s = 0; s < 16; ++s)
    wfB[s] = *reinterpret_cast<const bf16x8*>(
        Whh + (u64)colA * HID + kh * 512 + 32 * s + k4 * 8);
#pragma unroll
  for (int s = 0; s < 32; ++s) asm volatile("" : "+v"(wfA[s]));
#pragma unroll
  for (int s = 0; s < 16; ++s) asm volatile("" : "+v"(wfB[s]));

  // prefetched P values for the CURRENT step
  float pAc[4], pBc[4];
#pragma unroll
  for (int q = 0; q < 4; ++q) {
    int m = 4 * k4 + q;
    pAc[q] = bf2f(PA[((u64)(b0 + m) * TLEN) * HID + colA]);
    pBc[q] = bf2f(PhH[((u64)(b0 + m) * TLEN) * HID + colA]);
  }

  float hprev[4] = {0.f, 0.f, 0.f, 0.f};  // h(t-1) at (4*k4+q, colA), ALL waves

  for (int t = 0; t < TLEN; ++t) {
    const int par = t & 1;
    const u32 epN = (u32)(t + 1);  // epoch for values produced this step

    // ---- phase A input: poll-load h(t-1) (epoch t, parity (t-1)&1) ----
    if (t > 0) {
      const u32 ep = (u32)t;
      const u32* src = hxbuf32 + (u64)((t - 1) & 1) * (BATCHN * HID) +
                       (u64)(b0 + srow) * HID + soff;
      u64 tmp[32];
      for (;;) {
        bool ok = true;
#pragma unroll
        for (int i = 0; i < 32; ++i) tmp[i] = ld_dc64(src + i * 32);
#pragma unroll
        for (int i = 0; i < 32; ++i)
          ok &= (((u32)(tmp[i] >> 16) & 0xFFFFu) == ep) & ((u32)(tmp[i] >> 48) == ep);
        if (ok) break;
      }
      u16* dst = &hx[srow * HX_LD + soff];
#pragma unroll
      for (int i = 0; i < 32; ++i) {
        u32 packed = (u32)(tmp[i] & 0xFFFFu) | (((u32)(tmp[i] >> 32) & 0xFFFFu) << 16);
        *reinterpret_cast<u32*>(dst + i * 32) = packed;
      }
      __syncthreads();  // S1: hx staged (also: zL(t-1) reads done vs write below)
    }

    // ================= phase A: z,r = sigmoid(h @ W.T + P) =================
    f32x4 acc = {0.f, 0.f, 0.f, 0.f}, acc_b = {0.f, 0.f, 0.f, 0.f};
    if (t > 0) {
#pragma unroll
      for (int s = 0; s < 32; s += 2) {
        bf16x8 a0 = *reinterpret_cast<const bf16x8*>(&hx[l15 * HX_LD + 32 * s + k4 * 8]);
        bf16x8 a1 = *reinterpret_cast<const bf16x8*>(&hx[l15 * HX_LD + 32 * (s + 1) + k4 * 8]);
        acc   = __builtin_amdgcn_mfma_f32_16x16x32_bf16(a0, wfA[s],     acc,   0, 0, 0);
        acc_b = __builtin_amdgcn_mfma_f32_16x16x32_bf16(a1, wfA[s + 1], acc_b, 0, 0, 0);
      }
    }
#pragma unroll
    for (int q = 0; q < 4; ++q) {
      int m = 4 * k4 + q;
      float pre = acc[q] + acc_b[q] + pAc[q];
      float sg = 1.f / (1.f + __expf(-pre));
      if (gate == 0) {
        zL[m * ZL_LD + 16 * j + l15] = f2bf(sg);
      } else {
        u32 pv = (u32)f2bf(sg * hprev[q]) | (epN << 16);
        st_dc32(rhbuf32 + (u64)par * (BATCHN * HID) + (u64)(b0 + m) * HID + colA, pv);
      }
    }
    __syncthreads();  // S2: phase-A hx reads done (hx re-staged below); zL ready

    // ---- phase B input: poll-load rh (epoch t+1, parity t&1) ----
    {
      const u32* src = rhbuf32 + (u64)par * (BATCHN * HID) +
                       (u64)(b0 + srow) * HID + soff;
      u64 tmp[32];
      for (;;) {
        bool ok = true;
#pragma unroll
        for (int i = 0; i < 32; ++i) tmp[i] = ld_dc64(src + i * 32);
#pragma unroll
        for (int i = 0; i < 32; ++i)
          ok &= (((u32)(tmp[i] >> 16) & 0xFFFFu) == epN) & ((u32)(tmp[i] >> 48) == epN);
        if (ok) break;
      }
      u16* dst = &hx[srow * HX_LD + soff];
#pragma unroll
      for (int i = 0; i < 32; ++i) {
        u32 packed = (u32)(tmp[i] & 0xFFFFu) | (((u32)(tmp[i] >> 32) & 0xFFFFu) << 16);
        *reinterpret_cast<u32*>(dst + i * 32) = packed;
      }
      __syncthreads();  // S3: rh staged
    }

    // ========= phase B: htilde = tanh(rh @ Whh.T + Ph); h update =========
    f32x4 acc2 = {0.f, 0.f, 0.f, 0.f}, acc2b = {0.f, 0.f, 0.f, 0.f};
#pragma unroll
    for (int s = 0; s < 16; s += 2) {
      bf16x8 a0 = *reinterpret_cast<const bf16x8*>(
          &hx[l15 * HX_LD + kh * 512 + 32 * s + k4 * 8]);
      bf16x8 a1 = *reinterpret_cast<const bf16x8*>(
          &hx[l15 * HX_LD + kh * 512 + 32 * (s + 1) + k4 * 8]);
      acc2  = __builtin_amdgcn_mfma_f32_16x16x32_bf16(a0, wfB[s],     acc2,  0, 0, 0);
      acc2b = __builtin_amdgcn_mfma_f32_16x16x32_bf16(a1, wfB[s + 1], acc2b, 0, 0, 0);
    }
#pragma unroll
    for (int q = 0; q < 4; ++q) acc2[q] += acc2b[q];
    // exchange K-half partials; ALL waves compute identical h (add commutes)
    *reinterpret_cast<f32x4*>(&RED[(wid * 64 + lane) * 4]) = acc2;
    __syncthreads();  // S4
    {
      f32x4 part = *reinterpret_cast<const f32x4*>(&RED[((wid ^ 2) * 64 + lane) * 4]);
#pragma unroll
      for (int q = 0; q < 4; ++q) {
        int m = 4 * k4 + q;
        float pre = acc2[q] + part[q] + pBc[q];
        float e2 = __expf(2.f * pre);
        float th = 1.f - 2.f / (e2 + 1.f);  // tanh, inf-safe
        float zq = bf2f(zL[m * ZL_LD + 16 * j + l15]);
        float hn = (1.f - zq) * hprev[q] + zq * th;
        hprev[q] = hn;
        if (wid < 2) {
          u16 hb = f2bf(hn);
          // epoch-tagged h for the next step's poll
          st_dc32(hxbuf32 + (u64)par * (BATCHN * HID) + (u64)(b0 + m) * HID + colA,
                  (u32)hb | (epN << 16));
          // plain bf16 h for out_gemm (visible at kernel end)
          PhH[((u64)(b0 + m) * TLEN + t) * HID + colA] = hb;
        }
      }
    }
    // prefetch P for t+1 (plain cached loads; overlap the next poll)
    {
      int tn = (t + 1 < TLEN) ? (t + 1) : t;
#pragma unroll
      for (int q = 0; q < 4; ++q) {
        int m = 4 * k4 + q;
        pAc[q] = bf2f(PA[((u64)(b0 + m) * TLEN + tn) * HID + colA]);
        pBc[q] = bf2f(PhH[((u64)(b0 + m) * TLEN + tn) * HID + colA]);
      }
    }
  }
}

// ---------------- host ----------------
extern "C" void kernel_launch(void* const* d_in, const int* in_sizes, int n_in,
                              void* d_out, int out_size, void* d_ws, size_t ws_size,
                              hipStream_t stream) {
  const float* word = (const float*)d_in[0];
  const float* Wz = (const float*)d_in[1];
  const float* bz = (const float*)d_in[2];
  const float* Wr = (const float*)d_in[3];
  const float* br = (const float*)d_in[4];
  const float* Wh = (const float*)d_in[5];
  const float* bh = (const float*)d_in[6];
  const float* Wy = (const float*)d_in[7];
  const float* by = (const float*)d_in[8];
  float* out = (float*)d_out;
  (void)in_sizes; (void)n_in; (void)out_size; (void)ws_size;

  char* ws = (char*)d_ws;
  size_t off = 0;
  auto alloc = [&](size_t bytes) {
    char* p = ws + off;
    off += (bytes + 255) & ~(size_t)255;
    return p;
  };
  u32* rhbuf32 = (u32*)alloc((size_t)2 * BATCHN * HID * 4);  // 512 KB
  u32* hxbuf32 = (u32*)alloc((size_t)2 * BATCHN * HID * 4);  // 512 KB
  u16* WzhB = (u16*)alloc((size_t)HID * HID * 2);
  u16* WrhB = (u16*)alloc((size_t)HID * HID * 2);
  u16* WhhB = (u16*)alloc((size_t)HID * HID * 2);
  u16* WzxB = (u16*)alloc((size_t)HID * EMB * 2);
  u16* WrxB = (u16*)alloc((size_t)HID * EMB * 2);
  u16* WhxB = (u16*)alloc((size_t)HID * EMB * 2);
  u16* WyB  = (u16*)alloc((size_t)EMB * HID * 2);
  u16* Pr   = (u16*)alloc((size_t)BATCHN * TLEN * HID * 2);
  u16* PhH  = (u16*)alloc((size_t)BATCHN * TLEN * HID * 2);
  // total ws use ~138 MiB
  u16* Pz = (u16*)d_out;  // overlay: 32768x1024 bf16 == 32768x512 fp32; dead
                          // before out_gemm overwrites d_out.

  // zero epochs: garbage/0xAA never matches a valid epoch (1..512)
  hipMemsetAsync(rhbuf32, 0, (size_t)4 * BATCHN * HID * 4, stream);

  convert_gate_w<<<(HID * CAT + 255) / 256, 256, 0, stream>>>(Wz, WzhB, WzxB);
  convert_gate_w<<<(HID * CAT + 255) / 256, 256, 0, stream>>>(Wr, WrhB, WrxB);
  convert_gate_w<<<(HID * CAT + 255) / 256, 256, 0, stream>>>(Wh, WhhB, WhxB);
  convert_wy<<<(EMB * HID + 255) / 256, 256, 0, stream>>>(Wy, WyB);

  dim3 pg(512, 16);
  proj_kernel<<<pg, 256, 0, stream>>>(word, WzxB, bz, Pz);
  proj_kernel<<<pg, 256, 0, stream>>>(word, WrxB, br, Pr);
  proj_kernel<<<pg, 256, 0, stream>>>(word, WhxB, bh, PhH);

  gru_persistent<<<dim3(GROUPS * WPG), dim3(256), 0, stream>>>(WzhB, WrhB, WhhB, Pz, Pr, PhH,
                                                               rhbuf32, hxbuf32);

  out_gemm<<<dim3(512, 8), 256, 0, stream>>>(PhH, WyB, by, out);
}

// Round 11
// 2941.329 us; speedup vs baseline: 1.3565x; 1.3565x over previous
//
#include <hip/hip_runtime.h>
#include <hip/hip_bf16.h>

// GRU restructured (v11): v9 base (best: 2.69 ms) + critical-path surgery.
//   - Prefetch P(t+1) moved INSIDE the barrier window (after flag store, before
//     poll): its RTT no longer delays the flag -> off the global critical path.
//   - hx XOR swizzle (e ^= (row&7)<<3, 16B blocks) + HX_LD=1024: A-frag
//     ds_read_b128 banks uniform 8/bank (was up to 16), staging writes 4/bank.
//   - poll without s_sleep.
//   Everything else = v9: pinned weights (asm "+v"), LDS-staged coop exchange
//   loads (batched agent u64 atomics), direct st_dc16 gate stores, flag
//   barrier with relaxed agent atomics, all-wave redundant h finalize via RED.

#define EMB 512
#define HID 1024
#define BATCHN 64
#define TLEN 512
#define CAT 1536
#define GROUPS 4
#define GB 16
#define WPG 32            // WGs per group (each owns 32 cols)
#define HX_LD 1024        // swizzled layout, no pad needed
#define ZL_LD 34
#define GPAD 8

typedef __attribute__((ext_vector_type(8))) short bf16x8;
typedef __attribute__((ext_vector_type(4))) short s16x4;
typedef __attribute__((ext_vector_type(4))) float f32x4;
typedef unsigned int u32;
typedef unsigned long long u64;
typedef unsigned short u16;

__device__ __forceinline__ float bf2f(u16 u) {
  union { float f; u32 i; } v; v.i = ((u32)u) << 16; return v.f;
}
__device__ __forceinline__ u16 f2bf(float f) {
  union { float f; u32 i; } v; v.f = f;
  u32 r = v.i + 0x7fffu + ((v.i >> 16) & 1u);
  return (u16)(r >> 16);
}

// Agent-scope relaxed atomics (verified primitives, v4-v9).
__device__ __forceinline__ u64 ld_dc(const u16* p) {
  return __hip_atomic_load((const u64*)p, __ATOMIC_RELAXED, __HIP_MEMORY_SCOPE_AGENT);
}
__device__ __forceinline__ void st_dc16(u16* p, u16 v) {
  __hip_atomic_store(p, v, __ATOMIC_RELAXED, __HIP_MEMORY_SCOPE_AGENT);
}

// ---------------- phase 0: weight conversion ----------------
__global__ __launch_bounds__(256) void convert_gate_w(const float* __restrict__ W,
                                                      u16* __restrict__ Wh_,
                                                      u16* __restrict__ Wx_) {
  int i = blockIdx.x * 256 + threadIdx.x;
  if (i >= HID * CAT) return;
  int row = i / CAT, col = i - row * CAT;
  u16 v = f2bf(W[i]);
  if (col < HID) Wh_[row * HID + col] = v;
  else           Wx_[row * EMB + (col - HID)] = v;
}

__global__ __launch_bounds__(256) void convert_wy(const float* __restrict__ W, u16* __restrict__ Wy_) {
  int i = blockIdx.x * 256 + threadIdx.x;
  if (i < EMB * HID) Wy_[i] = f2bf(W[i]);
}

// ---------------- phase 1: P = shift(word) @ Wx.T + bias ----------------
__global__ __launch_bounds__(256) void proj_kernel(const float* __restrict__ word,
                                                   const u16* __restrict__ Wx,
                                                   const float* __restrict__ bias,
                                                   u16* __restrict__ P) {
  __shared__ __align__(16) u16 As[64][64 + GPAD];
  __shared__ __align__(16) u16 Bs[64][64 + GPAD];
  const int tid = threadIdx.x;
  const int wid = tid >> 6, lane = tid & 63;
  const int m0 = blockIdx.x * 64, n0 = blockIdx.y * 64;
  const int mw = (wid >> 1) * 32, nw = (wid & 1) * 32;
  f32x4 acc[2][2] = {};
  for (int k0 = 0; k0 < EMB; k0 += 64) {
#pragma unroll
    for (int it = 0; it < 4; ++it) {
      int e = (it * 256 + tid) * 4;
      int row = e >> 6, col = e & 63;
      int R = m0 + row;
      float4 a = make_float4(0.f, 0.f, 0.f, 0.f);
      if ((R & (TLEN - 1)) != 0)
        a = *reinterpret_cast<const float4*>(&word[(u64)(R - 1) * EMB + k0 + col]);
      s16x4 vv;
      vv[0] = (short)f2bf(a.x); vv[1] = (short)f2bf(a.y);
      vv[2] = (short)f2bf(a.z); vv[3] = (short)f2bf(a.w);
      *reinterpret_cast<s16x4*>(&As[row][col]) = vv;
    }
#pragma unroll
    for (int it = 0; it < 2; ++it) {
      int e = (it * 256 + tid) * 8;
      int row = e >> 6, col = e & 63;
      *reinterpret_cast<bf16x8*>(&Bs[row][col]) =
          *reinterpret_cast<const bf16x8*>(&Wx[(u64)(n0 + row) * EMB + k0 + col]);
    }
    __syncthreads();
#pragma unroll
    for (int kk = 0; kk < 2; ++kk) {
      const int kb = kk * 32 + 8 * (lane >> 4);
#pragma unroll
      for (int i = 0; i < 2; ++i) {
        bf16x8 a = *reinterpret_cast<const bf16x8*>(&As[mw + i * 16 + (lane & 15)][kb]);
#pragma unroll
        for (int j = 0; j < 2; ++j) {
          bf16x8 b = *reinterpret_cast<const bf16x8*>(&Bs[nw + j * 16 + (lane & 15)][kb]);
          acc[i][j] = __builtin_amdgcn_mfma_f32_16x16x32_bf16(a, b, acc[i][j], 0, 0, 0);
        }
      }
    }
    __syncthreads();
  }
#pragma unroll
  for (int i = 0; i < 2; ++i)
#pragma unroll
    for (int j = 0; j < 2; ++j) {
      int col = n0 + nw + j * 16 + (lane & 15);
      float bv = bias[col];
#pragma unroll
      for (int q = 0; q < 4; ++q) {
        int row = m0 + mw + i * 16 + 4 * (lane >> 4) + q;
        P[(u64)row * HID + col] = f2bf(acc[i][j][q] + bv);
      }
    }
}

// ---------------- phase 3: out = H @ Wy.T + by (fp32 out) ----------------
__global__ __launch_bounds__(256) void out_gemm(const u16* __restrict__ H,
                                                const u16* __restrict__ Wy,
                                                const float* __restrict__ by,
                                                float* __restrict__ out) {
  __shared__ __align__(16) u16 As[64][64 + GPAD];
  __shared__ __align__(16) u16 Bs[64][64 + GPAD];
  const int tid = threadIdx.x;
  const int wid = tid >> 6, lane = tid & 63;
  const int m0 = blockIdx.x * 64, n0 = blockIdx.y * 64;
  const int mw = (wid >> 1) * 32, nw = (wid & 1) * 32;
  f32x4 acc[2][2] = {};
  for (int k0 = 0; k0 < HID; k0 += 64) {
#pragma unroll
    for (int it = 0; it < 2; ++it) {
      int e = (it * 256 + tid) * 8;
      int row = e >> 6, col = e & 63;
      *reinterpret_cast<bf16x8*>(&As[row][col]) =
          *reinterpret_cast<const bf16x8*>(&H[(u64)(m0 + row) * HID + k0 + col]);
      *reinterpret_cast<bf16x8*>(&Bs[row][col]) =
          *reinterpret_cast<const bf16x8*>(&Wy[(u64)(n0 + row) * HID + k0 + col]);
    }
    __syncthreads();
#pragma unroll
    for (int kk = 0; kk < 2; ++kk) {
      const int kb = kk * 32 + 8 * (lane >> 4);
#pragma unroll
      for (int i = 0; i < 2; ++i) {
        bf16x8 a = *reinterpret_cast<const bf16x8*>(&As[mw + i * 16 + (lane & 15)][kb]);
#pragma unroll
        for (int j = 0; j < 2; ++j) {
          bf16x8 b = *reinterpret_cast<const bf16x8*>(&Bs[nw + j * 16 + (lane & 15)][kb]);
          acc[i][j] = __builtin_amdgcn_mfma_f32_16x16x32_bf16(a, b, acc[i][j], 0, 0, 0);
        }
      }
    }
    __syncthreads();
  }
#pragma unroll
  for (int i = 0; i < 2; ++i)
#pragma unroll
    for (int j = 0; j < 2; ++j) {
      int col = n0 + nw + j * 16 + (lane & 15);
      float bv = by[col];
#pragma unroll
      for (int q = 0; q < 4; ++q) {
        int row = m0 + mw + i * 16 + 4 * (lane >> 4) + q;
        out[(u64)row * EMB + col] = acc[i][j][q] + bv;
      }
    }
}

// ---------------- phase 2: persistent recurrent kernel ----------------
// Poll helper (no sleep): lanes poll the 32 slots in parallel.
__device__ __forceinline__ void poll_flags(u32* gflags, u32 target) {
  if (threadIdx.x < 64) {
    u32* addr = &gflags[((int)threadIdx.x & (WPG - 1)) * 16];
    for (;;) {
      u32 v = __hip_atomic_load(addr, __ATOMIC_RELAXED, __HIP_MEMORY_SCOPE_AGENT);
      if (!__any((int)(v < target))) break;
    }
  }
}

__global__ __launch_bounds__(256, 1) void gru_persistent(
    const u16* __restrict__ Wzh, const u16* __restrict__ Wrh, const u16* __restrict__ Whh,
    const u16* __restrict__ Pz, const u16* __restrict__ Pr, u16* __restrict__ PhH,
    u16* __restrict__ rhbuf, u32* flags) {
  // LDS ~37.9 KB: hx (coop-load staging, swizzled) + zL + RED.
  __shared__ __align__(16) u16 hx[16 * HX_LD];
  __shared__ __align__(16) u16 zL[16 * ZL_LD];
  __shared__ __align__(16) float RED[4 * 64 * 4];

  const int tid = threadIdx.x;
  const int wid = tid >> 6;
  const int lane = tid & 63;
  const int l15 = lane & 15;
  const int k4 = lane >> 4;  // 0..3
  const int g = blockIdx.x & (GROUPS - 1);
  const int w = blockIdx.x >> 2;  // 0..31, owns cols [32w, 32w+32)
  const int b0 = g * GB;
  const int j = wid & 1;        // 16-col tile within the 32
  const int gate = wid >> 1;    // stage A: 0 = z, 1 = r
  const int kh = wid >> 1;      // stage B: K-half
  const int colA = 32 * w + 16 * j + l15;
  const u16* __restrict__ PA = gate ? Pr : Pz;
  u32* gflags = flags + g * (WPG * 16);

  // hx XOR swizzle: element offset e in row r maps to e ^ ((r&7)<<3)
  // (16B blocks permute within 128B windows). Verified uniform banks for
  // A-frag b128 reads (8/bank), B reads (8/bank), staging b64 writes (4/bank).
  const int sw = (l15 & 7) << 3;

  // staging decomposition for coop loads: thread (srow, soff), 16 u64 chunks at
  // element soff + i*64 -> 128B-coalesced global reads.
  const int srow = tid >> 4;
  const int soff = (tid & 15) * 4;
  const int ssw = (srow & 7) << 3;

  // ---- weights -> registers, PINNED (asm "+v" blocks rematerialization) ----
  bf16x8 wfA[32];  // 16 cols of Wzh (waves 0-1) or Wrh (waves 2-3), full K
#pragma unroll
  for (int s = 0; s < 32; ++s)
    wfA[s] = *reinterpret_cast<const bf16x8*>(
        (gate ? Wrh : Wzh) + (u64)colA * HID + 32 * s + k4 * 8);
  bf16x8 wfB[16];  // 16 cols of Whh, K-half kh
#pragma unroll
  for (int s = 0; s < 16; ++s)
    wfB[s] = *reinterpret_cast<const bf16x8*>(
        Whh + (u64)colA * HID + kh * 512 + 32 * s + k4 * 8);
#pragma unroll
  for (int s = 0; s < 32; ++s) asm volatile("" : "+v"(wfA[s]));
#pragma unroll
  for (int s = 0; s < 16; ++s) asm volatile("" : "+v"(wfB[s]));

  // zero hx (h(-1) = 0; swizzle-invariant)
  for (int e = tid; e < 16 * HX_LD / 2; e += 256) reinterpret_cast<u32*>(hx)[e] = 0u;
  __syncthreads();

  // prefetched P values for the CURRENT step
  float pAc[4], pBc[4];
#pragma unroll
  for (int q = 0; q < 4; ++q) {
    int m = 4 * k4 + q;
    pAc[q] = bf2f(PA[((u64)(b0 + m) * TLEN) * HID + colA]);
    pBc[q] = bf2f(PhH[((u64)(b0 + m) * TLEN) * HID + colA]);
  }

  float hprev[4] = {0.f, 0.f, 0.f, 0.f};  // h(t-1) at (4*k4+q, colA), ALL waves
  u32 ph = 0;

  for (int t = 0; t < TLEN; ++t) {
    // ---- cooperative load h(t-1) -> hx (batched agent u64 loads) ----
    if (t > 0) {
      const u16* src = PhH + ((u64)(b0 + srow) * TLEN + (t - 1)) * HID + soff;
      u64 tmp[16];
#pragma unroll
      for (int i = 0; i < 16; ++i) tmp[i] = ld_dc(src + i * 64);
      u16* dst = &hx[srow * HX_LD];
#pragma unroll
      for (int i = 0; i < 16; ++i)
        *reinterpret_cast<u64*>(dst + ((soff + i * 64) ^ ssw)) = tmp[i];
      __syncthreads();
    }

    // ================= phase A: z,r = sigmoid(h @ W.T + P) =================
    f32x4 acc = {0.f, 0.f, 0.f, 0.f}, acc_b = {0.f, 0.f, 0.f, 0.f};
    if (t > 0) {
#pragma unroll
      for (int s = 0; s < 32; s += 2) {
        bf16x8 a0 = *reinterpret_cast<const bf16x8*>(
            &hx[l15 * HX_LD + ((32 * s + k4 * 8) ^ sw)]);
        bf16x8 a1 = *reinterpret_cast<const bf16x8*>(
            &hx[l15 * HX_LD + ((32 * (s + 1) + k4 * 8) ^ sw)]);
        acc   = __builtin_amdgcn_mfma_f32_16x16x32_bf16(a0, wfA[s],     acc,   0, 0, 0);
        acc_b = __builtin_amdgcn_mfma_f32_16x16x32_bf16(a1, wfA[s + 1], acc_b, 0, 0, 0);
      }
    }
#pragma unroll
    for (int q = 0; q < 4; ++q) {
      int m = 4 * k4 + q;
      float pre = acc[q] + acc_b[q] + pAc[q];
      float sg = 1.f / (1.f + __expf(-pre));
      if (gate == 0) {
        zL[m * ZL_LD + 16 * j + l15] = f2bf(sg);
      } else {
        st_dc16(rhbuf + (u64)(g * GB + m) * HID + colA, f2bf(sg * hprev[q]));
      }
    }

    // ---- barrier A: sync (drains rh stores) -> flag -> prefetch pA -> poll ----
    ++ph;
    __syncthreads();
    asm volatile("" ::: "memory");
    if (tid == w)
      __hip_atomic_store(&gflags[w * 16], ph, __ATOMIC_RELAXED, __HIP_MEMORY_SCOPE_AGENT);
    {
      int tn = (t + 1 < TLEN) ? (t + 1) : t;
#pragma unroll
      for (int q = 0; q < 4; ++q) {
        int m = 4 * k4 + q;
        pAc[q] = bf2f(PA[((u64)(b0 + m) * TLEN + tn) * HID + colA]);
      }
    }
    poll_flags(gflags, ph);
    __syncthreads();
    asm volatile("" ::: "memory");

    // ---- cooperative load rh -> hx ----
    {
      const u16* src = rhbuf + (u64)(g * GB + srow) * HID + soff;
      u64 tmp[16];
#pragma unroll
      for (int i = 0; i < 16; ++i) tmp[i] = ld_dc(src + i * 64);
      u16* dst = &hx[srow * HX_LD];
#pragma unroll
      for (int i = 0; i < 16; ++i)
        *reinterpret_cast<u64*>(dst + ((soff + i * 64) ^ ssw)) = tmp[i];
      __syncthreads();
    }

    // ========= phase B: htilde = tanh(rh @ Whh.T + Ph); h update =========
    f32x4 acc2 = {0.f, 0.f, 0.f, 0.f}, acc2b = {0.f, 0.f, 0.f, 0.f};
#pragma unroll
    for (int s = 0; s < 16; s += 2) {
      bf16x8 a0 = *reinterpret_cast<const bf16x8*>(
          &hx[l15 * HX_LD + ((kh * 512 + 32 * s + k4 * 8) ^ sw)]);
      bf16x8 a1 = *reinterpret_cast<const bf16x8*>(
          &hx[l15 * HX_LD + ((kh * 512 + 32 * (s + 1) + k4 * 8) ^ sw)]);
      acc2  = __builtin_amdgcn_mfma_f32_16x16x32_bf16(a0, wfB[s],     acc2,  0, 0, 0);
      acc2b = __builtin_amdgcn_mfma_f32_16x16x32_bf16(a1, wfB[s + 1], acc2b, 0, 0, 0);
    }
#pragma unroll
    for (int q = 0; q < 4; ++q) acc2[q] += acc2b[q];
    // exchange K-half partials; ALL waves compute identical h (add commutes)
    *reinterpret_cast<f32x4*>(&RED[(wid * 64 + lane) * 4]) = acc2;
    __syncthreads();
    {
      f32x4 part = *reinterpret_cast<const f32x4*>(&RED[((wid ^ 2) * 64 + lane) * 4]);
#pragma unroll
      for (int q = 0; q < 4; ++q) {
        int m = 4 * k4 + q;
        float pre = acc2[q] + part[q] + pBc[q];
        float e2 = __expf(2.f * pre);
        float th = 1.f - 2.f / (e2 + 1.f);  // tanh, inf-safe
        float zq = bf2f(zL[m * ZL_LD + 16 * j + l15]);
        float hn = (1.f - zq) * hprev[q] + zq * th;
        hprev[q] = hn;
        if (wid < 2)  // direct store h(t) -> PhH[t] (in-place over Ph)
          st_dc16(PhH + ((u64)(b0 + m) * TLEN + t) * HID + colA, f2bf(hn));
      }
    }

    // ---- barrier B: sync (drains h stores) -> flag -> prefetch pB -> poll ----
    ++ph;
    __syncthreads();
    asm volatile("" ::: "memory");
    if (tid == w)
      __hip_atomic_store(&gflags[w * 16], ph, __ATOMIC_RELAXED, __HIP_MEMORY_SCOPE_AGENT);
    {
      int tn = (t + 1 < TLEN) ? (t + 1) : t;
#pragma unroll
      for (int q = 0; q < 4; ++q) {
        int m = 4 * k4 + q;
        pBc[q] = bf2f(PhH[((u64)(b0 + m) * TLEN + tn) * HID + colA]);
      }
    }
    poll_flags(gflags, ph);
    __syncthreads();
    asm volatile("" ::: "memory");
  }
}

// ---------------- host ----------------
extern "C" void kernel_launch(void* const* d_in, const int* in_sizes, int n_in,
                              void* d_out, int out_size, void* d_ws, size_t ws_size,
                              hipStream_t stream) {
  const float* word = (const float*)d_in[0];
  const float* Wz = (const float*)d_in[1];
  const float* bz = (const float*)d_in[2];
  const float* Wr = (const float*)d_in[3];
  const float* br = (const float*)d_in[4];
  const float* Wh = (const float*)d_in[5];
  const float* bh = (const float*)d_in[6];
  const float* Wy = (const float*)d_in[7];
  const float* by = (const float*)d_in[8];
  float* out = (float*)d_out;
  (void)in_sizes; (void)n_in; (void)out_size; (void)ws_size;

  char* ws = (char*)d_ws;
  size_t off = 0;
  auto alloc = [&](size_t bytes) {
    char* p = ws + off;
    off += (bytes + 255) & ~(size_t)255;
    return p;
  };
  u32* flags = (u32*)alloc(GROUPS * WPG * 16 * sizeof(u32));  // 8 KB
  u16* WzhB = (u16*)alloc((size_t)HID * HID * 2);
  u16* WrhB = (u16*)alloc((size_t)HID * HID * 2);
  u16* WhhB = (u16*)alloc((size_t)HID * HID * 2);
  u16* WzxB = (u16*)alloc((size_t)HID * EMB * 2);
  u16* WrxB = (u16*)alloc((size_t)HID * EMB * 2);
  u16* WhxB = (u16*)alloc((size_t)HID * EMB * 2);
  u16* WyB  = (u16*)alloc((size_t)EMB * HID * 2);
  u16* Pr   = (u16*)alloc((size_t)BATCHN * TLEN * HID * 2);
  u16* PhH  = (u16*)alloc((size_t)BATCHN * TLEN * HID * 2);
  u16* rhbuf = (u16*)alloc((size_t)GROUPS * GB * HID * 2);
  // total ws use ~138 MiB
  u16* Pz = (u16*)d_out;  // overlay: 32768x1024 bf16 == 32768x512 fp32; dead
                          // before out_gemm overwrites d_out.

  hipMemsetAsync(flags, 0, GROUPS * WPG * 16 * sizeof(u32), stream);

  convert_gate_w<<<(HID * CAT + 255) / 256, 256, 0, stream>>>(Wz, WzhB, WzxB);
  convert_gate_w<<<(HID * CAT + 255) / 256, 256, 0, stream>>>(Wr, WrhB, WrxB);
  convert_gate_w<<<(HID * CAT + 255) / 256, 256, 0, stream>>>(Wh, WhhB, WhxB);
  convert_wy<<<(EMB * HID + 255) / 256, 256, 0, stream>>>(Wy, WyB);

  dim3 pg(512, 16);
  proj_kernel<<<pg, 256, 0, stream>>>(word, WzxB, bz, Pz);
  proj_kernel<<<pg, 256, 0, stream>>>(word, WrxB, br, Pr);
  proj_kernel<<<pg, 256, 0, stream>>>(word, WhxB, bh, PhH);

  gru_persistent<<<dim3(GROUPS * WPG), dim3(256), 0, stream>>>(WzhB, WrhB, WhhB, Pz, Pr, PhH,
                                                               rhbuf, flags);

  out_gemm<<<dim3(512, 8), 256, 0, stream>>>(PhH, WyB, by, out);
}